// Round 2
// baseline (59.986 us; speedup 1.0000x reference)
//
#include <hip/hip_runtime.h>

// Sliding-window min (STL Always_[16,64]):
//   out[t][b] = min_{j=15..63} xpad[t-j][b],   xpad[s<0] = 1e6
// Window width 49 along T. Memory-bound; floor = 134 MB read + 134 MB write.
// R2: float2 (8 B/lane) loads/stores — dword-only vmem tops out ~70% of the
// achievable 6.3 TB/s; x2/x4 widths are what the BW ubench ceiling uses.

#define T_DIM 8192
#define B_DIM 4096
#define C_TILE 32               // outputs per thread along T
#define ALEN (C_TILE + 48)      // inputs per thread (window width 49)
#define LARGE_VAL 1e6f

__device__ __forceinline__ float2 fmin2(float2 a, float2 b) {
    return make_float2(fminf(a.x, b.x), fminf(a.y, b.y));
}

__global__ __launch_bounds__(256)
void Temporal_Operator_kernel(const float* __restrict__ x,
                              float* __restrict__ out) {
    const int c2 = blockIdx.x * blockDim.x + threadIdx.x;   // float2 column
    const int t0 = blockIdx.y * C_TILE;                     // output tile start
    const long base = (long)t0 - 63;                        // first input row
    const int ROW2 = B_DIM / 2;                             // row stride in float2

    const float2* __restrict__ xp = (const float2*)x;
    float2* __restrict__ op = (float2*)out;

    // Load inputs (negative rows -> LARGE). Fully unrolled: static indices keep
    // arr[] in VGPRs; the s>=0 predicate is wave-uniform (only y-tiles 0,1).
    float2 arr[ALEN];
    #pragma unroll
    for (int i = 0; i < ALEN; ++i) {
        long s = base + i;
        arr[i] = (s >= 0) ? xp[s * ROW2 + c2]
                          : make_float2(LARGE_VAL, LARGE_VAL);
    }

    // Log-doubling forward window mins, in place:
    // after pass k, arr[i] = min(x[i .. i+k-1]) over the valid range.
    #pragma unroll
    for (int i = 0; i < ALEN - 1; ++i)  arr[i] = fmin2(arr[i], arr[i + 1]);   // w2
    #pragma unroll
    for (int i = 0; i < ALEN - 3; ++i)  arr[i] = fmin2(arr[i], arr[i + 2]);   // w4
    #pragma unroll
    for (int i = 0; i < ALEN - 7; ++i)  arr[i] = fmin2(arr[i], arr[i + 4]);   // w8
    #pragma unroll
    for (int i = 0; i < ALEN - 15; ++i) arr[i] = fmin2(arr[i], arr[i + 8]);   // w16
    #pragma unroll
    for (int i = 0; i < ALEN - 31; ++i) arr[i] = fmin2(arr[i], arr[i + 16]);  // w32

    // w49[c] = min(w32[c], w32[c+17])  covers [c, c+48]
    #pragma unroll
    for (int c = 0; c < C_TILE; ++c) {
        op[(long)(t0 + c) * ROW2 + c2] = fmin2(arr[c], arr[c + 17]);
    }
}

extern "C" void kernel_launch(void* const* d_in, const int* in_sizes, int n_in,
                              void* d_out, int out_size, void* d_ws, size_t ws_size,
                              hipStream_t stream) {
    const float* x = (const float*)d_in[0];
    float* out = (float*)d_out;

    dim3 block(256, 1, 1);
    dim3 grid((B_DIM / 2) / 256, T_DIM / C_TILE, 1);   // 8 x 256 blocks
    Temporal_Operator_kernel<<<grid, block, 0, stream>>>(x, out);
}

// Round 3
// 56.904 us; speedup vs baseline: 1.0542x; 1.0542x over previous
//
#include <hip/hip_runtime.h>

// Sliding-window min (STL Always_[16,64]):
//   out[t][b] = min_{j=15..63} xpad[t-j][b],   xpad[s<0] = 1e6
// R3: C_TILE 32 -> 128. Halo re-read amplification (C_TILE+48)/C_TILE drops
// 2.5x -> 1.375x. R1 evidence: compiler streams the in-place cascade with a
// live set bounded by window depth (44 VGPR @ ALEN=80), so big ALEN is cheap.
// Scalar loads (R1): float2 (R2) proved width-neutral and costs occupancy.

#define T_DIM 8192
#define B_DIM 4096
#define C_TILE 128              // outputs per thread along T
#define ALEN (C_TILE + 48)      // inputs per thread (window width 49)
#define LARGE_VAL 1e6f

__global__ __launch_bounds__(256)
void Temporal_Operator_kernel(const float* __restrict__ x,
                              float* __restrict__ out) {
    const int b  = blockIdx.x * blockDim.x + threadIdx.x;   // column
    const int t0 = blockIdx.y * C_TILE;                     // output tile start
    const long base = (long)t0 - 63;                        // first input row

    // Load inputs (negative rows -> LARGE; predicate is wave-uniform, only
    // y-block 0). Fully unrolled: static indices keep arr[] in VGPRs.
    float arr[ALEN];
    #pragma unroll
    for (int i = 0; i < ALEN; ++i) {
        long s = base + i;
        arr[i] = (s >= 0) ? x[s * B_DIM + b] : LARGE_VAL;
    }

    // Log-doubling forward window mins, in place:
    // after pass k, arr[i] = min(x[i .. i+k-1]) over the valid range.
    #pragma unroll
    for (int i = 0; i < ALEN - 1; ++i)  arr[i] = fminf(arr[i], arr[i + 1]);   // w2
    #pragma unroll
    for (int i = 0; i < ALEN - 3; ++i)  arr[i] = fminf(arr[i], arr[i + 2]);   // w4
    #pragma unroll
    for (int i = 0; i < ALEN - 7; ++i)  arr[i] = fminf(arr[i], arr[i + 4]);   // w8
    #pragma unroll
    for (int i = 0; i < ALEN - 15; ++i) arr[i] = fminf(arr[i], arr[i + 8]);   // w16
    #pragma unroll
    for (int i = 0; i < ALEN - 31; ++i) arr[i] = fminf(arr[i], arr[i + 16]);  // w32

    // w49[c] = min(w32[c], w32[c+17])  covers [c, c+48]
    #pragma unroll
    for (int c = 0; c < C_TILE; ++c) {
        out[(long)(t0 + c) * B_DIM + b] = fminf(arr[c], arr[c + 17]);
    }
}

extern "C" void kernel_launch(void* const* d_in, const int* in_sizes, int n_in,
                              void* d_out, int out_size, void* d_ws, size_t ws_size,
                              hipStream_t stream) {
    const float* x = (const float*)d_in[0];
    float* out = (float*)d_out;

    dim3 block(256, 1, 1);
    dim3 grid(B_DIM / 256, T_DIM / C_TILE, 1);   // 16 x 64 blocks
    Temporal_Operator_kernel<<<grid, block, 0, stream>>>(x, out);
}

// Round 4
// 56.063 us; speedup vs baseline: 1.0700x; 1.0150x over previous
//
#include <hip/hip_runtime.h>

// Sliding-window min (STL Always_[16,64]):
//   out[t][b] = min_{j=15..63} xpad[t-j][b],   xpad[s<0] = 1e6
// R4: nontemporal stores. R1-R3 showed time is invariant (~57-60us) to load
// width, occupancy, and fabric-traffic amplification -> hypothesis: the 134MB
// output write-allocates in L2/L3 and thrashes the 134MB input out of the
// 256MiB Infinity Cache (268MB working set > L3). Streaming stores (nt) leave
// L3 to the input; warm replays should read mostly from L3 and pay HBM only
// for writes.

#define T_DIM 8192
#define B_DIM 4096
#define C_TILE 128              // outputs per thread along T
#define ALEN (C_TILE + 48)      // inputs per thread (window width 49)
#define LARGE_VAL 1e6f

__global__ __launch_bounds__(256)
void Temporal_Operator_kernel(const float* __restrict__ x,
                              float* __restrict__ out) {
    const int b  = blockIdx.x * blockDim.x + threadIdx.x;   // column
    const int t0 = blockIdx.y * C_TILE;                     // output tile start
    const long base = (long)t0 - 63;                        // first input row

    // Load inputs (negative rows -> LARGE; predicate is wave-uniform, only
    // y-block 0). Fully unrolled: static indices keep arr[] in VGPRs.
    float arr[ALEN];
    #pragma unroll
    for (int i = 0; i < ALEN; ++i) {
        long s = base + i;
        arr[i] = (s >= 0) ? x[s * B_DIM + b] : LARGE_VAL;
    }

    // Log-doubling forward window mins, in place:
    // after pass k, arr[i] = min(x[i .. i+k-1]) over the valid range.
    #pragma unroll
    for (int i = 0; i < ALEN - 1; ++i)  arr[i] = fminf(arr[i], arr[i + 1]);   // w2
    #pragma unroll
    for (int i = 0; i < ALEN - 3; ++i)  arr[i] = fminf(arr[i], arr[i + 2]);   // w4
    #pragma unroll
    for (int i = 0; i < ALEN - 7; ++i)  arr[i] = fminf(arr[i], arr[i + 4]);   // w8
    #pragma unroll
    for (int i = 0; i < ALEN - 15; ++i) arr[i] = fminf(arr[i], arr[i + 8]);   // w16
    #pragma unroll
    for (int i = 0; i < ALEN - 31; ++i) arr[i] = fminf(arr[i], arr[i + 16]);  // w32

    // w49[c] = min(w32[c], w32[c+17]) covers [c, c+48]; stream past caches.
    #pragma unroll
    for (int c = 0; c < C_TILE; ++c) {
        __builtin_nontemporal_store(fminf(arr[c], arr[c + 17]),
                                    &out[(long)(t0 + c) * B_DIM + b]);
    }
}

extern "C" void kernel_launch(void* const* d_in, const int* in_sizes, int n_in,
                              void* d_out, int out_size, void* d_ws, size_t ws_size,
                              hipStream_t stream) {
    const float* x = (const float*)d_in[0];
    float* out = (float*)d_out;

    dim3 block(256, 1, 1);
    dim3 grid(B_DIM / 256, T_DIM / C_TILE, 1);   // 16 x 64 blocks
    Temporal_Operator_kernel<<<grid, block, 0, stream>>>(x, out);
}